// Round 29
// baseline (110.454 us; speedup 1.0000x reference)
//
#include <hip/hip_runtime.h>

#define T_LEN  4096
#define KS     16
#define NSEG   8           // T segments (512 output steps each)
#define SEG_CH 32          // output chunks per segment
#define WARM_CH 20         // 320 warm-up steps (validated R26/R28)
#define USTRIDE 18         // u-row stride in dwords: 2-way bank aliasing, 8B-aligned

#define ALPHA_F 0.9048374180359595f
#define BETA_F  0.09516258196404048f
#define THETA_F 0.5f

// LDS-only barrier (R28-proven neutral-or-better): drains LDS ops but not
// global traffic. The only cross-wave dependency is the dbuf LDS ring.
__device__ __forceinline__ void barrier_lds() {
  asm volatile("s_waitcnt lgkmcnt(0)\n\ts_barrier" ::: "memory");
}

// Full-wave (64-lane) max, result in ALL lanes. Verbatim from the passing
// R3-R28 kernels (manual s_nop hazard handling inside asm).
__device__ __forceinline__ float wave64_max_all(float v) {
  float m, t;
  asm("s_nop 1\n\t"
      "v_max_f32 %0, %2, %2 quad_perm:[1,0,3,2] row_mask:0xf bank_mask:0xf\n\t"
      "s_nop 1\n\t"
      "v_max_f32 %0, %0, %0 quad_perm:[2,3,0,1] row_mask:0xf bank_mask:0xf\n\t"
      "s_nop 1\n\t"
      "v_max_f32 %0, %0, %0 row_half_mirror row_mask:0xf bank_mask:0xf\n\t"
      "s_nop 1\n\t"
      "v_max_f32 %0, %0, %0 row_mirror row_mask:0xf bank_mask:0xf\n\t"
      "v_mov_b32 %1, %0\n\t"
      "s_nop 1\n\t"
      "v_permlane32_swap_b32 %1, %0\n\t"
      "s_nop 1\n\t"
      "v_max_f32 %0, %0, %1\n\t"
      "v_mov_b32 %1, %0\n\t"
      "s_nop 1\n\t"
      "v_permlane16_swap_b32 %1, %0\n\t"
      "s_nop 1\n\t"
      "v_max_f32 %0, %0, %1"
      : "=&v"(m), "=&v"(t)
      : "v"(v));
  return m;
}

__global__ __launch_bounds__(128, 4)
void convlif_wta_kernel(const float* __restrict__ x, const float* __restrict__ W,
                        float* __restrict__ out) {
  const int blk  = blockIdx.x;
  const int b    = blk >> 3;          // batch
  const int seg  = blk & (NSEG - 1);  // time segment
  const int wave = threadIdx.x >> 6;  // 0 = consumer (LIF+convHI), 1 = producer
  const int lane = threadIdx.x & 63;  // channel k

  const int cout0  = seg * SEG_CH;                                  // first output chunk
  const int cstart = (cout0 > WARM_CH) ? (cout0 - WARM_CH) : 0;     // warm-up start
  const int cend   = cout0 + SEG_CH;
  const int wpairs = (cout0 - cstart) >> 1;  // 10 (seg>0) or 0 (seg 0)
  const int npair  = (cend - cstart) >> 1;   // 26 (seg>0) or 16 (seg 0)

  // u handoff ring: [slot][chunk-of-pair][lane][i]; stride 18 dwords ->
  // float2 8B-aligned, 2-way bank aliasing (free). 18 KB/block -> 8 blocks/CU.
  // [slot][1] carries only u[0..7] (c1's LO half; HI computed by consumer).
  __shared__ float dbuf[2][2][64][USTRIDE];

  const float4* xv4 = reinterpret_cast<const float4*>(x + (size_t)b * T_LEN);
  float* orow = out + ((size_t)(b * 64 + lane)) * T_LEN;   // this lane's channel row

  // per-lane conv weights W[k][0..15] — both waves need them now
  float w[KS];
  {
    const float4* w4 = reinterpret_cast<const float4*>(W + lane * KS);
    #pragma unroll
    for (int q = 0; q < 4; ++q) {
      float4 a = w4[q];
      w[4*q+0] = a.x; w[4*q+1] = a.y; w[4*q+2] = a.z; w[4*q+3] = a.w;
    }
  }

  if (wave == 1) {
    // ======== producer: conv_full(c0) + conv_LO(c1) per pair ==============
    for (int p = 0; p < npair; ++p) {
      const int c0 = cstart + 2 * p;
      const int c1 = c0 + 1;

      // ---- full conv for c0 (verbatim summation order, all passing rounds)
      {
        float xf[32];
        if (c0 == 0) {
          #pragma unroll
          for (int m = 0; m < 16; ++m) xf[m] = 0.0f;
        } else {
          const int b4 = 4 * c0 - 4;
          #pragma unroll
          for (int q = 0; q < 4; ++q) {
            float4 a = xv4[b4 + q];
            xf[4*q+0] = a.x; xf[4*q+1] = a.y; xf[4*q+2] = a.z; xf[4*q+3] = a.w;
          }
        }
        #pragma unroll
        for (int q = 0; q < 4; ++q) {
          float4 a = xv4[4*c0 + q];
          xf[16+4*q+0] = a.x; xf[16+4*q+1] = a.y;
          xf[16+4*q+2] = a.z; xf[16+4*q+3] = a.w;
        }
        float* ur = &dbuf[p & 1][0][lane][0];
        #pragma unroll
        for (int i = 0; i < 16; i += 2) {
          float acc0 = w[0] * xf[1 + i];
          #pragma unroll
          for (int j = 1; j < KS; ++j) acc0 = fmaf(w[j], xf[1 + i + j], acc0);
          float acc1 = w[0] * xf[2 + i];
          #pragma unroll
          for (int j = 1; j < KS; ++j) acc1 = fmaf(w[j], xf[2 + i + j], acc1);
          *reinterpret_cast<float2*>(ur + i) =
              make_float2(BETA_F * acc0, BETA_F * acc1);
        }
      }

      // ---- LO conv for c1: outputs 0..7 need xf[1..23] -> quads 4c1-4..4c1+1
      // (c1 >= 1 always). Same per-output j-order -> bit-identical u.
      {
        float xf[24];
        const int b4 = 4 * c1 - 4;
        #pragma unroll
        for (int q = 0; q < 6; ++q) {
          float4 a = xv4[b4 + q];
          xf[4*q+0] = a.x; xf[4*q+1] = a.y; xf[4*q+2] = a.z; xf[4*q+3] = a.w;
        }
        float* ur = &dbuf[p & 1][1][lane][0];
        #pragma unroll
        for (int i = 0; i < 8; i += 2) {
          float acc0 = w[0] * xf[1 + i];
          #pragma unroll
          for (int j = 1; j < KS; ++j) acc0 = fmaf(w[j], xf[1 + i + j], acc0);
          float acc1 = w[0] * xf[2 + i];
          #pragma unroll
          for (int j = 1; j < KS; ++j) acc1 = fmaf(w[j], xf[2 + i + j], acc1);
          *reinterpret_cast<float2*>(ur + i) =
              make_float2(BETA_F * acc0, BETA_F * acc1);
        }
      }
      barrier_lds();     // pair p published
    }
    barrier_lds();       // final interval
  } else {
    // ==== consumer: conv_HI(c1) + serial LIF over the pair ================
    float v = 0.0f;      // exact for seg 0 (no warm); speculative else
    barrier_lds();       // interval 0: producer fills pair 0

    for (int q = 0; q < npair; ++q) {
      const int slot = q & 1;
      const int c0 = cstart + 2 * q;
      const int c1 = c0 + 1;
      const bool outp = (q >= wpairs);   // uniform per pair (wpairs even split)

      // u(c0) and u(c1)[0..7] from the ring
      float u0[16], u1lo[8];
      {
        const float* ur0 = &dbuf[slot][0][lane][0];
        #pragma unroll
        for (int i = 0; i < 16; i += 2) {
          float2 t2 = *reinterpret_cast<const float2*>(ur0 + i);
          u0[i] = t2.x; u0[i + 1] = t2.y;
        }
        const float* ur1 = &dbuf[slot][1][lane][0];
        #pragma unroll
        for (int i = 0; i < 8; i += 2) {
          float2 t2 = *reinterpret_cast<const float2*>(ur1 + i);
          u1lo[i] = t2.x; u1lo[i + 1] = t2.y;
        }
      }

      // HI window for c1: xh[t] = xf[8+t] = x[16*c1 - 8 + t], t=0..23
      // -> quads 4c1-2 .. 4c1+3 (c1 >= 1 -> all >= 2, in range)
      float xh[24];
      {
        const int bq = 4 * c1 - 2;
        #pragma unroll
        for (int qq = 0; qq < 6; ++qq) {
          float4 a = xv4[bq + qq];
          xh[4*qq+0] = a.x; xh[4*qq+1] = a.y; xh[4*qq+2] = a.z; xh[4*qq+3] = a.w;
        }
      }

      // conv HI of c1: outputs i=8..15; taps xf[1+i+j] = xh[i-7+j].
      // Same per-output j-order -> bit-identical u. These 8 independent FMA
      // chains are scheduler fodder that fills the LIF chain stalls below.
      float uhi[8];
      #pragma unroll
      for (int i = 8; i < 16; ++i) {
        float acc = w[0] * xh[i - 7];
        #pragma unroll
        for (int j = 1; j < KS; ++j) acc = fmaf(w[j], xh[i - 7 + j], acc);
        uhi[i - 8] = BETA_F * acc;
      }

      // ---- LIF chunk c0 (verbatim body; lean in warm) ----
      if (outp) {
        float sv[16];
        #pragma unroll
        for (int i = 0; i < 16; ++i) {
          float vr = fmaf(ALPHA_F, v, u0[i]);
          float vm = vr - THETA_F;
          unsigned long long sp = __ballot(vr >= THETA_F);
          bool c1b = (vr >= THETA_F);
          sv[i] = c1b ? 1.0f : 0.0f;
          v     = c1b ? vm : vr;
          if (__builtin_expect((sp & (sp - 1ull)) != 0ull, 0)) {
            float m = wave64_max_all(vr);
            unsigned long long eq = __ballot(vr == m);
            bool win = (lane == __builtin_ctzll(eq));
            sv[i] = win ? 1.0f : 0.0f;
            v     = win ? vm : vr;
          }
        }
        float4* pp = reinterpret_cast<float4*>(orow + (size_t)c0 * 16);
        pp[0] = make_float4(sv[0],  sv[1],  sv[2],  sv[3]);
        pp[1] = make_float4(sv[4],  sv[5],  sv[6],  sv[7]);
        pp[2] = make_float4(sv[8],  sv[9],  sv[10], sv[11]);
        pp[3] = make_float4(sv[12], sv[13], sv[14], sv[15]);
      } else {
        #pragma unroll
        for (int i = 0; i < 16; ++i) {
          float vr = fmaf(ALPHA_F, v, u0[i]);
          float vm = vr - THETA_F;
          unsigned long long sp = __ballot(vr >= THETA_F);
          bool c1b = (vr >= THETA_F);
          v = c1b ? vm : vr;
          if (__builtin_expect((sp & (sp - 1ull)) != 0ull, 0)) {
            float m = wave64_max_all(vr);
            unsigned long long eq = __ballot(vr == m);
            bool win = (lane == __builtin_ctzll(eq));
            v = win ? vm : vr;
          }
        }
      }

      // ---- LIF chunk c1 (u = lo from ring, hi computed above) ----
      if (outp) {
        float sv[16];
        #pragma unroll
        for (int i = 0; i < 16; ++i) {
          float ui = (i < 8) ? u1lo[i] : uhi[i - 8];   // static selection
          float vr = fmaf(ALPHA_F, v, ui);
          float vm = vr - THETA_F;
          unsigned long long sp = __ballot(vr >= THETA_F);
          bool c1b = (vr >= THETA_F);
          sv[i] = c1b ? 1.0f : 0.0f;
          v     = c1b ? vm : vr;
          if (__builtin_expect((sp & (sp - 1ull)) != 0ull, 0)) {
            float m = wave64_max_all(vr);
            unsigned long long eq = __ballot(vr == m);
            bool win = (lane == __builtin_ctzll(eq));
            sv[i] = win ? 1.0f : 0.0f;
            v     = win ? vm : vr;
          }
        }
        float4* pp = reinterpret_cast<float4*>(orow + (size_t)c1 * 16);
        pp[0] = make_float4(sv[0],  sv[1],  sv[2],  sv[3]);
        pp[1] = make_float4(sv[4],  sv[5],  sv[6],  sv[7]);
        pp[2] = make_float4(sv[8],  sv[9],  sv[10], sv[11]);
        pp[3] = make_float4(sv[12], sv[13], sv[14], sv[15]);
      } else {
        #pragma unroll
        for (int i = 0; i < 16; ++i) {
          float ui = (i < 8) ? u1lo[i] : uhi[i - 8];
          float vr = fmaf(ALPHA_F, v, ui);
          float vm = vr - THETA_F;
          unsigned long long sp = __ballot(vr >= THETA_F);
          bool c1b = (vr >= THETA_F);
          v = c1b ? vm : vr;
          if (__builtin_expect((sp & (sp - 1ull)) != 0ull, 0)) {
            float m = wave64_max_all(vr);
            unsigned long long eq = __ballot(vr == m);
            bool win = (lane == __builtin_ctzll(eq));
            v = win ? vm : vr;
          }
        }
      }

      barrier_lds();     // done with this slot; producer may rewrite it
    }
  }
}

extern "C" void kernel_launch(void* const* d_in, const int* in_sizes, int n_in,
                              void* d_out, int out_size, void* d_ws, size_t ws_size,
                              hipStream_t stream) {
  const float* x   = (const float*)d_in[0];
  const float* W   = (const float*)d_in[1];
  float*       out = (float*)d_out;
  convlif_wta_kernel<<<dim3(256 * NSEG), dim3(128), 0, stream>>>(x, W, out);
}